// Round 3
// baseline (104.884 us; speedup 1.0000x reference)
//
#include <hip/hip_runtime.h>
#include <math.h>

#define LL 1024
#define DD 512
#define HH 256
#define HL (HH * LL)

// ws layout (floats):
//   pt  : [2][H][L]  @ 0        t-partials, b1 folded into z=0
//   pu  : [2][H][L]  @ 2*HL     u-partials
//   sraw: [L][L]     @ 4*HL
// total ~2.1M floats = 8.4 MiB

// ---------------------------------------------------------------------------
// Kernel 1: GEMM. tile 64i x 16h, K-chunk 256. grid (16,16,2)=512 blocks
// -> 2 blocks/CU, 2 waves/SIMD. Each thread: 4 i-rows x 1 h, dual output.
// b1 folded in at z==0. Reads S/W1 direct from L2 (no LDS staging needed:
// wave pattern = 16 lines/s-load, 4 lines/w-load, heavy broadcast).
// ---------------------------------------------------------------------------
__global__ __launch_bounds__(256) void sp_gemm(
    const float* __restrict__ S, const float* __restrict__ W1,
    const float* __restrict__ b1,
    float* __restrict__ pt, float* __restrict__ pu) {
  const int iy = threadIdx.x & 15;    // i-group
  const int hx = threadIdx.x >> 4;    // h within tile
  const int i0 = blockIdx.x * 64;
  const int h0 = blockIdx.y * 16;
  const int k0 = blockIdx.z * 256;
  const int h  = h0 + hx;

  const float* sp = S  + (size_t)(i0 + 4 * iy) * DD + k0;
  const float* wp = W1 + (size_t)h * (2 * DD) + k0;

  float at[4] = {0.f, 0.f, 0.f, 0.f};
  float au[4] = {0.f, 0.f, 0.f, 0.f};

  #pragma unroll 4
  for (int kk = 0; kk < 256; kk += 4) {
    const float4 wa = *(const float4*)(wp + kk);
    const float4 wb = *(const float4*)(wp + DD + kk);
    #pragma unroll
    for (int a = 0; a < 4; ++a) {
      const float4 s = *(const float4*)(sp + (size_t)a * DD + kk);
      at[a] += s.x * wa.x + s.y * wa.y + s.z * wa.z + s.w * wa.w;
      au[a] += s.x * wb.x + s.y * wb.y + s.z * wb.z + s.w * wb.w;
    }
  }

  if (blockIdx.z == 0) {
    const float bb = b1[h];
    at[0] += bb; at[1] += bb; at[2] += bb; at[3] += bb;
  }

  const size_t zoff = (size_t)blockIdx.z * HL;
  *(float4*)(pt + zoff + (size_t)h * LL + i0 + 4 * iy) =
      make_float4(at[0], at[1], at[2], at[3]);
  *(float4*)(pu + zoff + (size_t)h * LL + i0 + 4 * iy) =
      make_float4(au[0], au[1], au[2], au[3]);
}

// ---------------------------------------------------------------------------
// Kernel 2: pairwise relu-dot, summing the 2 K-partials during LDS staging.
// tile 64x64, 4x4 per thread, grid (16,16)=256 blocks.
// ---------------------------------------------------------------------------
__global__ __launch_bounds__(256) void sp_pairwise(
    const float* __restrict__ pt, const float* __restrict__ pu,
    const float* __restrict__ W2, float* __restrict__ sraw) {
  __shared__ float Tl[HH][72];
  __shared__ float Ul[HH][72];

  const int tx = threadIdx.x & 15;
  const int ty = threadIdx.x >> 4;
  const int i0 = blockIdx.y * 64;
  const int j0 = blockIdx.x * 64;

  #pragma unroll
  for (int s = 0; s < 16; ++s) {
    const int m = s * 256 + threadIdx.x;
    const int h = m >> 4;
    const int g = m & 15;
    const size_t ti = (size_t)h * LL + i0 + 4 * g;
    const size_t uj = (size_t)h * LL + j0 + 4 * g;
    const float4 t0 = *(const float4*)(pt + ti);
    const float4 t1 = *(const float4*)(pt + HL + ti);
    const float4 u0 = *(const float4*)(pu + uj);
    const float4 u1 = *(const float4*)(pu + HL + uj);
    *(float4*)&Tl[h][4 * g] =
        make_float4(t0.x + t1.x, t0.y + t1.y, t0.z + t1.z, t0.w + t1.w);
    *(float4*)&Ul[h][4 * g] =
        make_float4(u0.x + u1.x, u0.y + u1.y, u0.z + u1.z, u0.w + u1.w);
  }
  __syncthreads();

  float acc[4][4] = {{0.f}};

  #pragma unroll 8
  for (int h = 0; h < HH; ++h) {
    const float4 tv4 = *(const float4*)&Tl[h][4 * ty];
    const float4 uv4 = *(const float4*)&Ul[h][4 * tx];
    const float w = W2[h];
    const float tv[4] = {tv4.x, tv4.y, tv4.z, tv4.w};
    const float uv[4] = {uv4.x, uv4.y, uv4.z, uv4.w};
    #pragma unroll
    for (int a = 0; a < 4; ++a) {
      #pragma unroll
      for (int b = 0; b < 4; ++b) {
        acc[a][b] = fmaf(fmaxf(tv[a] + uv[b], 0.f), w, acc[a][b]);
      }
    }
  }

  #pragma unroll
  for (int a = 0; a < 4; ++a) {
    float4 v = make_float4(acc[a][0], acc[a][1], acc[a][2], acc[a][3]);
    *(float4*)(sraw + (size_t)(i0 + 4 * ty + a) * LL + j0 + 4 * tx) = v;
  }
}

// ---------------------------------------------------------------------------
// Kernel 3: out = sigmoid(0.5*(s + s^T) + b2). 64x64 tiles, grid (16,16).
// LDS transpose with pad-65 -> 2-way (free) bank aliasing.
// ---------------------------------------------------------------------------
__global__ __launch_bounds__(256) void sp_symsig(
    const float* __restrict__ sraw, const float* __restrict__ b2,
    float* __restrict__ out) {
  __shared__ float B[64][65];
  const int i0 = blockIdx.y * 64;
  const int j0 = blockIdx.x * 64;
  const int r16 = threadIdx.x >> 4;  // 0..15
  const int g   = threadIdx.x & 15;  // 0..15

  // stage the mirrored tile (rows j0.., cols i0..)
  #pragma unroll
  for (int a = 0; a < 4; ++a) {
    const int row = a * 16 + r16;
    const float4 v = *(const float4*)(sraw + (size_t)(j0 + row) * LL + i0 + 4 * g);
    B[row][4 * g + 0] = v.x;
    B[row][4 * g + 1] = v.y;
    B[row][4 * g + 2] = v.z;
    B[row][4 * g + 3] = v.w;
  }
  __syncthreads();

  const float bb = b2[0];
  #pragma unroll
  for (int a = 0; a < 4; ++a) {
    const int row = a * 16 + r16;
    const float4 v = *(const float4*)(sraw + (size_t)(i0 + row) * LL + j0 + 4 * g);
    float4 o;
    float x;
    x = 0.5f * (v.x + B[4 * g + 0][row]) + bb; o.x = 1.f / (1.f + expf(-x));
    x = 0.5f * (v.y + B[4 * g + 1][row]) + bb; o.y = 1.f / (1.f + expf(-x));
    x = 0.5f * (v.z + B[4 * g + 2][row]) + bb; o.z = 1.f / (1.f + expf(-x));
    x = 0.5f * (v.w + B[4 * g + 3][row]) + bb; o.w = 1.f / (1.f + expf(-x));
    *(float4*)(out + (size_t)(i0 + row) * LL + j0 + 4 * g) = o;
  }
}

// ---------------------------------------------------------------------------
extern "C" void kernel_launch(void* const* d_in, const int* in_sizes, int n_in,
                              void* d_out, int out_size, void* d_ws, size_t ws_size,
                              hipStream_t stream) {
  const float* S  = (const float*)d_in[0];   // [L, D]
  const float* W1 = (const float*)d_in[1];   // [H, 2D]
  const float* b1 = (const float*)d_in[2];   // [H]
  const float* W2 = (const float*)d_in[3];   // [1, H]
  const float* b2 = (const float*)d_in[4];   // [1]
  float* out = (float*)d_out;

  float* ws = (float*)d_ws;
  float* pt   = ws;              // [2][H][L]
  float* pu   = ws + 2 * HL;     // [2][H][L]
  float* sraw = ws + 4 * HL;     // [L][L]

  hipLaunchKernelGGL(sp_gemm, dim3(16, 16, 2), dim3(256), 0, stream,
                     S, W1, b1, pt, pu);
  hipLaunchKernelGGL(sp_pairwise, dim3(16, 16), dim3(256), 0, stream,
                     pt, pu, W2, sraw);
  hipLaunchKernelGGL(sp_symsig, dim3(16, 16), dim3(256), 0, stream,
                     sraw, b2, out);
}

// Round 4
// 87.245 us; speedup vs baseline: 1.2022x; 1.2022x over previous
//
#include <hip/hip_runtime.h>
#include <math.h>

#define LL 1024
#define DD 512
#define HH 256
#define HL (HH * LL)

// ws layout (floats):
//   pt  : [4][H][L]  @ 0        t-partials (K-split 4), b1 folded into z=0
//   pu  : [4][H][L]  @ 4*HL     u-partials
//   sraw: [L][L]     @ 8*HL
// total 12 MiB

// ---------------------------------------------------------------------------
// Kernel 1: LDS-staged double-buffered fp32 GEMM (dot-product form).
// tT[h][i] = sum_k W1[h][k]*S[i][k]; uT[h][i] = sum_k W1[h][512+k]*S[i][k].
// Tile: 32h x 128i x 128k. grid (8 i-blk, 8 h-blk, 4 k-blk) = 256 blocks,
// 512 threads = 8 waves/CU = 2 waves/SIMD. K-chunks of 32, global->reg->LDS
// double-buffer, next chunk's loads issued before compute (latency hidden).
// LDS pad 36 (q=9 odd) -> staging writes and compute reads bank-uniform.
// ---------------------------------------------------------------------------
__global__ __launch_bounds__(512) void sp_gemm(
    const float* __restrict__ S, const float* __restrict__ W1,
    const float* __restrict__ b1,
    float* __restrict__ pt, float* __restrict__ pu) {
  __shared__ float Sl[2][128][36];
  __shared__ float Wl[2][2][32][36];

  const int tid = threadIdx.x;
  const int tx  = tid & 15;        // i sub-lane (i = tx + 16a)
  const int ty  = tid >> 4;        // h 0..31
  const int i0  = blockIdx.x * 128;
  const int h0  = blockIdx.y * 32;
  const int k0  = blockIdx.z * 128;

  // staging coords (per 32-k chunk: S 128x32 = 1024 f4, W 2x32x32 = 512 f4)
  const int srow = tid >> 3;       // 0..63
  const int sc   = tid & 7;        // 0..7  (k float4 within chunk)
  const int wmat = tid >> 8;       // 0..1
  const int wrow = (tid >> 3) & 31;

  float4 sA, sB, wA;

  auto ld = [&](int c) {
    const int kk = k0 + 32 * c;
    sA = *(const float4*)(S + (size_t)(i0 + srow) * DD + kk + 4 * sc);
    sB = *(const float4*)(S + (size_t)(i0 + 64 + srow) * DD + kk + 4 * sc);
    wA = *(const float4*)(W1 + (size_t)(h0 + wrow) * (2 * DD) + wmat * DD + kk + 4 * sc);
  };
  auto st = [&](int b) {
    *(float4*)&Sl[b][srow][4 * sc]       = sA;
    *(float4*)&Sl[b][64 + srow][4 * sc]  = sB;
    *(float4*)&Wl[b][wmat][wrow][4 * sc] = wA;
  };

  float at[8], au[8];
  #pragma unroll
  for (int a = 0; a < 8; ++a) { at[a] = 0.f; au[a] = 0.f; }

  ld(0);
  st(0);
  __syncthreads();

  for (int c = 0; c < 4; ++c) {
    const int cur = c & 1;
    if (c < 3) ld(c + 1);            // loads fly under compute
    #pragma unroll
    for (int k4 = 0; k4 < 8; ++k4) {
      const float4 wt = *(const float4*)&Wl[cur][0][ty][4 * k4];
      const float4 wu = *(const float4*)&Wl[cur][1][ty][4 * k4];
      #pragma unroll
      for (int a = 0; a < 8; ++a) {
        const float4 s = *(const float4*)&Sl[cur][tx + 16 * a][4 * k4];
        at[a] += s.x * wt.x + s.y * wt.y + s.z * wt.z + s.w * wt.w;
        au[a] += s.x * wu.x + s.y * wu.y + s.z * wu.z + s.w * wu.w;
      }
    }
    if (c < 3) st(cur ^ 1);          // cur^1 free since barrier of iter c-1
    __syncthreads();
  }

  const float bb = (blockIdx.z == 0) ? b1[h0 + ty] : 0.f;
  const size_t zo = (size_t)blockIdx.z * HL;
  float* pth = pt + zo + (size_t)(h0 + ty) * LL + i0 + tx;
  float* puh = pu + zo + (size_t)(h0 + ty) * LL + i0 + tx;
  #pragma unroll
  for (int a = 0; a < 8; ++a) {
    pth[16 * a] = at[a] + bb;
    puh[16 * a] = au[a];
  }
}

// ---------------------------------------------------------------------------
// Kernel 2: pairwise relu-dot. tile 64x64, 512 threads (2 waves/SIMD),
// grid (16,16)=256 blocks = 1 block/CU. Sums the 4 K-partials in staging.
// Per thread: 2i x 4j outputs. LDS [256][72] pads -> conflict-free reads.
// ---------------------------------------------------------------------------
__global__ __launch_bounds__(512) void sp_pairwise(
    const float* __restrict__ pt, const float* __restrict__ pu,
    const float* __restrict__ W2, float* __restrict__ sraw) {
  __shared__ float Tl[HH][72];
  __shared__ float Ul[HH][72];

  const int tid = threadIdx.x;
  const int tx  = tid & 15;     // j-group (4 j)
  const int ty  = tid >> 4;     // i-group (2 i), 0..31
  const int i0  = blockIdx.y * 64;
  const int j0  = blockIdx.x * 64;

  #pragma unroll
  for (int s = 0; s < 8; ++s) {
    const int m = s * 512 + tid;      // 0..4095
    const int h = m >> 4;
    const int g = m & 15;
    const size_t ti = (size_t)h * LL + i0 + 4 * g;
    const size_t uj = (size_t)h * LL + j0 + 4 * g;
    const float4 t0 = *(const float4*)(pt + ti);
    const float4 t1 = *(const float4*)(pt + HL + ti);
    const float4 t2 = *(const float4*)(pt + 2 * (size_t)HL + ti);
    const float4 t3 = *(const float4*)(pt + 3 * (size_t)HL + ti);
    const float4 u0 = *(const float4*)(pu + uj);
    const float4 u1 = *(const float4*)(pu + HL + uj);
    const float4 u2 = *(const float4*)(pu + 2 * (size_t)HL + uj);
    const float4 u3 = *(const float4*)(pu + 3 * (size_t)HL + uj);
    *(float4*)&Tl[h][4 * g] = make_float4(t0.x + t1.x + t2.x + t3.x,
                                          t0.y + t1.y + t2.y + t3.y,
                                          t0.z + t1.z + t2.z + t3.z,
                                          t0.w + t1.w + t2.w + t3.w);
    *(float4*)&Ul[h][4 * g] = make_float4(u0.x + u1.x + u2.x + u3.x,
                                          u0.y + u1.y + u2.y + u3.y,
                                          u0.z + u1.z + u2.z + u3.z,
                                          u0.w + u1.w + u2.w + u3.w);
  }
  __syncthreads();

  float acc[2][4] = {{0.f}};

  #pragma unroll 8
  for (int h = 0; h < HH; ++h) {
    const float2 tv2 = *(const float2*)&Tl[h][2 * ty];
    const float4 uv4 = *(const float4*)&Ul[h][4 * tx];
    const float w = W2[h];
    const float tv[2] = {tv2.x, tv2.y};
    const float uv[4] = {uv4.x, uv4.y, uv4.z, uv4.w};
    #pragma unroll
    for (int a = 0; a < 2; ++a) {
      #pragma unroll
      for (int b = 0; b < 4; ++b) {
        acc[a][b] = fmaf(fmaxf(tv[a] + uv[b], 0.f), w, acc[a][b]);
      }
    }
  }

  #pragma unroll
  for (int a = 0; a < 2; ++a) {
    float4 v = make_float4(acc[a][0], acc[a][1], acc[a][2], acc[a][3]);
    *(float4*)(sraw + (size_t)(i0 + 2 * ty + a) * LL + j0 + 4 * tx) = v;
  }
}

// ---------------------------------------------------------------------------
// Kernel 3: out = sigmoid(0.5*(s + s^T) + b2). 64x64 tiles, grid (16,16).
// ---------------------------------------------------------------------------
__global__ __launch_bounds__(256) void sp_symsig(
    const float* __restrict__ sraw, const float* __restrict__ b2,
    float* __restrict__ out) {
  __shared__ float B[64][65];
  const int i0 = blockIdx.y * 64;
  const int j0 = blockIdx.x * 64;
  const int r16 = threadIdx.x >> 4;  // 0..15
  const int g   = threadIdx.x & 15;  // 0..15

  #pragma unroll
  for (int a = 0; a < 4; ++a) {
    const int row = a * 16 + r16;
    const float4 v = *(const float4*)(sraw + (size_t)(j0 + row) * LL + i0 + 4 * g);
    B[row][4 * g + 0] = v.x;
    B[row][4 * g + 1] = v.y;
    B[row][4 * g + 2] = v.z;
    B[row][4 * g + 3] = v.w;
  }
  __syncthreads();

  const float bb = b2[0];
  #pragma unroll
  for (int a = 0; a < 4; ++a) {
    const int row = a * 16 + r16;
    const float4 v = *(const float4*)(sraw + (size_t)(i0 + row) * LL + j0 + 4 * g);
    float4 o;
    float x;
    x = 0.5f * (v.x + B[4 * g + 0][row]) + bb; o.x = 1.f / (1.f + expf(-x));
    x = 0.5f * (v.y + B[4 * g + 1][row]) + bb; o.y = 1.f / (1.f + expf(-x));
    x = 0.5f * (v.z + B[4 * g + 2][row]) + bb; o.z = 1.f / (1.f + expf(-x));
    x = 0.5f * (v.w + B[4 * g + 3][row]) + bb; o.w = 1.f / (1.f + expf(-x));
    *(float4*)(out + (size_t)(i0 + row) * LL + j0 + 4 * g) = o;
  }
}

// ---------------------------------------------------------------------------
extern "C" void kernel_launch(void* const* d_in, const int* in_sizes, int n_in,
                              void* d_out, int out_size, void* d_ws, size_t ws_size,
                              hipStream_t stream) {
  const float* S  = (const float*)d_in[0];   // [L, D]
  const float* W1 = (const float*)d_in[1];   // [H, 2D]
  const float* b1 = (const float*)d_in[2];   // [H]
  const float* W2 = (const float*)d_in[3];   // [1, H]
  const float* b2 = (const float*)d_in[4];   // [1]
  float* out = (float*)d_out;

  float* ws = (float*)d_ws;
  float* pt   = ws;              // [4][H][L]
  float* pu   = ws + 4 * HL;     // [4][H][L]
  float* sraw = ws + 8 * HL;     // [L][L]

  hipLaunchKernelGGL(sp_gemm, dim3(8, 8, 4), dim3(512), 0, stream,
                     S, W1, b1, pt, pu);
  hipLaunchKernelGGL(sp_pairwise, dim3(16, 16), dim3(512), 0, stream,
                     pt, pu, W2, sraw);
  hipLaunchKernelGGL(sp_symsig, dim3(16, 16), dim3(256), 0, stream,
                     sraw, b2, out);
}

// Round 5
// 67.353 us; speedup vs baseline: 1.5572x; 1.2953x over previous
//
#include <hip/hip_runtime.h>
#include <math.h>

#define LL 1024
#define DD 512
#define HH 256

// ws layout (floats):
//   tT  : [H][L] @ 0        tT[h][i] = S[i]·W1[h,:512] + b1[h]
//   uT  : [H][L] @ HH*LL    uT[h][i] = S[i]·W1[h,512:]
//   sraw: [L][L] @ 2*HH*LL  raw scores
// total 6 MiB

// ---------------------------------------------------------------------------
// Kernel 1: full-K LDS GEMM. tile 64i x 16h, K=512 in 8 chunks of 64.
// 256 thr, grid (16,16)=256 blocks. Per thread: 4i x 1h x 2mat = 8 acc.
// S-tile XOR-swizzled (slot ^ row&15): linear would be 16-way bank conflict
// on the stride-64 row reads; swizzled is 2-way (free) both store & read.
// Small register footprint (6 prefetch f4 + 8 acc) -> no spill (r4 lesson).
// ---------------------------------------------------------------------------
__global__ __launch_bounds__(256) void sp_gemm(
    const float* __restrict__ S, const float* __restrict__ W1,
    const float* __restrict__ b1,
    float* __restrict__ tT, float* __restrict__ uT) {
  __shared__ float Sl[2][64][64];       // 32 KB
  __shared__ float Wl[2][2][16][64];    // 16 KB

  const int tid = threadIdx.x;
  const int tx  = tid & 15;     // i sub-lane: i = tx + 16a
  const int ty  = tid >> 4;     // h 0..15
  const int i0  = blockIdx.x * 64;
  const int h0  = blockIdx.y * 16;

  float4 sreg[4], wreg[2];

  auto ld = [&](int c) {
    const int kk = 64 * c;
    #pragma unroll
    for (int q = 0; q < 4; ++q) {
      const int m = q * 256 + tid;
      const int row = m >> 4, sl = m & 15;
      sreg[q] = *(const float4*)(S + (size_t)(i0 + row) * DD + kk + 4 * sl);
    }
    #pragma unroll
    for (int q = 0; q < 2; ++q) {
      const int m = q * 256 + tid;
      const int mat = m >> 8, r16 = (m >> 4) & 15, sl = m & 15;
      wreg[q] = *(const float4*)(W1 + (size_t)(h0 + r16) * (2 * DD) + mat * DD + kk + 4 * sl);
    }
  };
  auto st = [&](int b) {
    #pragma unroll
    for (int q = 0; q < 4; ++q) {
      const int m = q * 256 + tid;
      const int row = m >> 4, sl = m & 15;
      *(float4*)&Sl[b][row][4 * (sl ^ (row & 15))] = sreg[q];
    }
    #pragma unroll
    for (int q = 0; q < 2; ++q) {
      const int m = q * 256 + tid;
      const int mat = m >> 8, r16 = (m >> 4) & 15, sl = m & 15;
      *(float4*)&Wl[b][mat][r16][4 * sl] = wreg[q];
    }
  };

  float at[4] = {0.f, 0.f, 0.f, 0.f};
  float au[4] = {0.f, 0.f, 0.f, 0.f};

  ld(0); st(0); __syncthreads();

  for (int c = 0; c < 8; ++c) {
    const int cur = c & 1;
    if (c < 7) ld(c + 1);               // global loads fly under compute
    #pragma unroll 4
    for (int k4 = 0; k4 < 16; ++k4) {
      const float4 wt = *(const float4*)&Wl[cur][0][ty][4 * k4];
      const float4 wu = *(const float4*)&Wl[cur][1][ty][4 * k4];
      #pragma unroll
      for (int a = 0; a < 4; ++a) {
        const float4 s = *(const float4*)&Sl[cur][tx + 16 * a][4 * (k4 ^ tx)];
        at[a] += s.x * wt.x + s.y * wt.y + s.z * wt.z + s.w * wt.w;
        au[a] += s.x * wu.x + s.y * wu.y + s.z * wu.z + s.w * wu.w;
      }
    }
    if (c < 7) st(cur ^ 1);             // prev barrier freed buf cur^1
    __syncthreads();
  }

  const float bb = b1[h0 + ty];
  float* tp = tT + (size_t)(h0 + ty) * LL + i0 + tx;
  float* up = uT + (size_t)(h0 + ty) * LL + i0 + tx;
  #pragma unroll
  for (int a = 0; a < 4; ++a) {
    tp[16 * a] = at[a] + bb;
    up[16 * a] = au[a];
  }
}

// ---------------------------------------------------------------------------
// Kernel 2: pairwise. raw(i,j) = sum_h relu(t_i+u_j)*w = 0.5*(A_i+B_j+acc),
// acc = sum_h |t_i+u_j|*w, A_i = sum_h t_i*w, B_j = sum_h u_j*w.
// Inner loop: 2 VALU ops/(i,j,h) (add + fma with free |src| modifier).
// tile 64x64, 4x4/thread, 256 thr, grid (16,16).
// ---------------------------------------------------------------------------
__global__ __launch_bounds__(256) void sp_pairwise(
    const float* __restrict__ tT, const float* __restrict__ uT,
    const float* __restrict__ W2, float* __restrict__ sraw) {
  __shared__ float Tl[HH][72];
  __shared__ float Ul[HH][72];
  __shared__ float P[4][64];
  __shared__ float As[64], Bs[64];

  const int tid = threadIdx.x;
  const int tx  = tid & 15;
  const int ty  = tid >> 4;
  const int i0  = blockIdx.y * 64;
  const int j0  = blockIdx.x * 64;

  // stage panels (pure float4 copies; t/u stored transposed in ws)
  #pragma unroll
  for (int s = 0; s < 16; ++s) {
    const int m = s * 256 + tid;
    const int h = m >> 4;
    const int g = m & 15;
    *(float4*)&Tl[h][4 * g] = *(const float4*)(tT + (size_t)h * LL + i0 + 4 * g);
    *(float4*)&Ul[h][4 * g] = *(const float4*)(uT + (size_t)h * LL + j0 + 4 * g);
  }
  __syncthreads();

  // A prologue: A[i] = sum_h Tl[h][i]*w2[h]; 256 thr = 64 i x 4 h-quarters
  {
    const int il = tid & 63, hq = tid >> 6;
    float p = 0.f;
    #pragma unroll 4
    for (int n = 0; n < 64; ++n) {
      const int h = hq * 64 + n;
      p = fmaf(Tl[h][il], W2[h], p);
    }
    P[hq][il] = p;
  }
  __syncthreads();
  if (tid < 64) As[tid] = P[0][tid] + P[1][tid] + P[2][tid] + P[3][tid];
  __syncthreads();
  {
    const int il = tid & 63, hq = tid >> 6;
    float p = 0.f;
    #pragma unroll 4
    for (int n = 0; n < 64; ++n) {
      const int h = hq * 64 + n;
      p = fmaf(Ul[h][il], W2[h], p);
    }
    P[hq][il] = p;
  }
  __syncthreads();
  if (tid < 64) Bs[tid] = P[0][tid] + P[1][tid] + P[2][tid] + P[3][tid];
  __syncthreads();

  float acc[4][4] = {{0.f}};

  #pragma unroll 4
  for (int h = 0; h < HH; ++h) {
    const float4 tv4 = *(const float4*)&Tl[h][4 * ty];
    const float4 uv4 = *(const float4*)&Ul[h][4 * tx];
    const float w = W2[h];
    const float tv[4] = {tv4.x, tv4.y, tv4.z, tv4.w};
    const float uv[4] = {uv4.x, uv4.y, uv4.z, uv4.w};
    #pragma unroll
    for (int a = 0; a < 4; ++a) {
      #pragma unroll
      for (int b = 0; b < 4; ++b) {
        acc[a][b] = fmaf(fabsf(tv[a] + uv[b]), w, acc[a][b]);
      }
    }
  }

  #pragma unroll
  for (int a = 0; a < 4; ++a) {
    const float Ai = As[4 * ty + a];
    float4 v;
    v.x = 0.5f * (acc[a][0] + Ai + Bs[4 * tx + 0]);
    v.y = 0.5f * (acc[a][1] + Ai + Bs[4 * tx + 1]);
    v.z = 0.5f * (acc[a][2] + Ai + Bs[4 * tx + 2]);
    v.w = 0.5f * (acc[a][3] + Ai + Bs[4 * tx + 3]);
    *(float4*)(sraw + (size_t)(i0 + 4 * ty + a) * LL + j0 + 4 * tx) = v;
  }
}

// ---------------------------------------------------------------------------
// Kernel 3: out = sigmoid(0.5*(s + s^T) + b2). 64x64 tiles, grid (16,16).
// ---------------------------------------------------------------------------
__global__ __launch_bounds__(256) void sp_symsig(
    const float* __restrict__ sraw, const float* __restrict__ b2,
    float* __restrict__ out) {
  __shared__ float B[64][65];
  const int i0 = blockIdx.y * 64;
  const int j0 = blockIdx.x * 64;
  const int r16 = threadIdx.x >> 4;  // 0..15
  const int g   = threadIdx.x & 15;  // 0..15

  #pragma unroll
  for (int a = 0; a < 4; ++a) {
    const int row = a * 16 + r16;
    const float4 v = *(const float4*)(sraw + (size_t)(j0 + row) * LL + i0 + 4 * g);
    B[row][4 * g + 0] = v.x;
    B[row][4 * g + 1] = v.y;
    B[row][4 * g + 2] = v.z;
    B[row][4 * g + 3] = v.w;
  }
  __syncthreads();

  const float bb = b2[0];
  #pragma unroll
  for (int a = 0; a < 4; ++a) {
    const int row = a * 16 + r16;
    const float4 v = *(const float4*)(sraw + (size_t)(i0 + row) * LL + j0 + 4 * g);
    float4 o;
    float x;
    x = 0.5f * (v.x + B[4 * g + 0][row]) + bb; o.x = 1.f / (1.f + expf(-x));
    x = 0.5f * (v.y + B[4 * g + 1][row]) + bb; o.y = 1.f / (1.f + expf(-x));
    x = 0.5f * (v.z + B[4 * g + 2][row]) + bb; o.z = 1.f / (1.f + expf(-x));
    x = 0.5f * (v.w + B[4 * g + 3][row]) + bb; o.w = 1.f / (1.f + expf(-x));
    *(float4*)(out + (size_t)(i0 + row) * LL + j0 + 4 * g) = o;
  }
}

// ---------------------------------------------------------------------------
extern "C" void kernel_launch(void* const* d_in, const int* in_sizes, int n_in,
                              void* d_out, int out_size, void* d_ws, size_t ws_size,
                              hipStream_t stream) {
  const float* S  = (const float*)d_in[0];   // [L, D]
  const float* W1 = (const float*)d_in[1];   // [H, 2D]
  const float* b1 = (const float*)d_in[2];   // [H]
  const float* W2 = (const float*)d_in[3];   // [1, H]
  const float* b2 = (const float*)d_in[4];   // [1]
  float* out = (float*)d_out;

  float* ws = (float*)d_ws;
  float* tT   = ws;                  // [H][L]
  float* uT   = ws + HH * LL;        // [H][L]
  float* sraw = ws + 2 * HH * LL;    // [L][L]

  hipLaunchKernelGGL(sp_gemm, dim3(16, 16), dim3(256), 0, stream,
                     S, W1, b1, tT, uT);
  hipLaunchKernelGGL(sp_pairwise, dim3(16, 16), dim3(256), 0, stream,
                     tT, uT, W2, sraw);
  hipLaunchKernelGGL(sp_symsig, dim3(16, 16), dim3(256), 0, stream,
                     sraw, b2, out);
}

// Round 6
// 56.354 us; speedup vs baseline: 1.8611x; 1.1952x over previous
//
#include <hip/hip_runtime.h>
#include <math.h>

#define LL 1024
#define DD 512
#define HH 256

// ws layout (floats):
//   tT  : [H][L] @ 0        tT[h][i] = S[i]·W1[h,:512] + b1[h]
//   uT  : [H][L] @ HH*LL    uT[h][i] = S[i]·W1[h,512:]
//   sraw: [L][L] @ 2*HH*LL  raw scores
// total 6 MiB

// ---------------------------------------------------------------------------
// Kernel 1: full-K LDS GEMM. tile 32i x 16h, K=512 in 8 chunks of 64.
// 256 thr, grid (32,16)=512 blocks = 2 blocks/CU = 2 waves/SIMD (round-5 had
// 1/SIMD -> latency-starved). LDS 33 KB so both blocks fit. Per thread:
// 2i x 1h x 2mat = 4 acc, ~50 VGPR, no spill.
// S-tile XOR-swizzled (slot ^ row&15) -> 2-way (free) store & read.
// W-tile pad 68 -> the 4 ty-broadcast rows land on distinct banks.
// ---------------------------------------------------------------------------
__global__ __launch_bounds__(256) void sp_gemm(
    const float* __restrict__ S, const float* __restrict__ W1,
    const float* __restrict__ b1,
    float* __restrict__ tT, float* __restrict__ uT) {
  __shared__ float Sl[2][32][64];       // 16 KB
  __shared__ float Wl[2][2][16][68];    // 17 KB

  const int tid = threadIdx.x;
  const int ix  = tid & 15;     // i sub-lane: i = ix + 16a, a<2
  const int ty  = tid >> 4;     // h 0..15
  const int i0  = blockIdx.x * 32;
  const int h0  = blockIdx.y * 16;

  float4 sreg[2], wreg[2];

  auto ld = [&](int c) {
    const int kk = 64 * c;
    #pragma unroll
    for (int q = 0; q < 2; ++q) {
      const int m = q * 256 + tid;              // 0..511
      const int row = m >> 4, sl = m & 15;      // S: 32 rows x 16 f4
      sreg[q] = *(const float4*)(S + (size_t)(i0 + row) * DD + kk + 4 * sl);
      const int mat = m >> 8, r16 = (m >> 4) & 15;
      wreg[q] = *(const float4*)(W1 + (size_t)(h0 + r16) * (2 * DD) + mat * DD + kk + 4 * sl);
    }
  };
  auto st = [&](int b) {
    #pragma unroll
    for (int q = 0; q < 2; ++q) {
      const int m = q * 256 + tid;
      const int row = m >> 4, sl = m & 15;
      *(float4*)&Sl[b][row][4 * (sl ^ (row & 15))] = sreg[q];
      const int mat = m >> 8, r16 = (m >> 4) & 15;
      *(float4*)&Wl[b][mat][r16][4 * sl] = wreg[q];
    }
  };

  float at[2] = {0.f, 0.f};
  float au[2] = {0.f, 0.f};

  ld(0); st(0); __syncthreads();

  for (int c = 0; c < 8; ++c) {
    const int cur = c & 1;
    if (c < 7) ld(c + 1);               // global loads fly under compute
    #pragma unroll 4
    for (int k4 = 0; k4 < 16; ++k4) {
      const float4 wt = *(const float4*)&Wl[cur][0][ty][4 * k4];
      const float4 wu = *(const float4*)&Wl[cur][1][ty][4 * k4];
      #pragma unroll
      for (int a = 0; a < 2; ++a) {
        const float4 s = *(const float4*)&Sl[cur][ix + 16 * a][4 * (k4 ^ ix)];
        at[a] += s.x * wt.x + s.y * wt.y + s.z * wt.z + s.w * wt.w;
        au[a] += s.x * wu.x + s.y * wu.y + s.z * wu.z + s.w * wu.w;
      }
    }
    if (c < 7) st(cur ^ 1);             // prev barrier freed buf cur^1
    __syncthreads();
  }

  const float bb = b1[h0 + ty];
  float* tp = tT + (size_t)(h0 + ty) * LL + i0 + ix;
  float* up = uT + (size_t)(h0 + ty) * LL + i0 + ix;
  #pragma unroll
  for (int a = 0; a < 2; ++a) {
    tp[16 * a] = at[a] + bb;
    up[16 * a] = au[a];
  }
}

// ---------------------------------------------------------------------------
// Kernel 2: pairwise. raw(i,j) = 0.5*(A_i + B_j + sum_h |t_i+u_j|*w2_h),
// A_i = sum_h t_i*w2, B_j = sum_h u_j*w2 (relu(x) = 0.5(x+|x|), exact).
// 1024 threads (16 waves/CU = 4/SIMD; round-5 had 1/SIMD at VALUBusy 35%).
// tile 64x64, per-thread 1i x 4j: scalar t broadcast + float4 u.
// grid (16,16)=256 blocks, LDS ~152 KB (1 block/CU).
// ---------------------------------------------------------------------------
__global__ __launch_bounds__(1024) void sp_pairwise(
    const float* __restrict__ tT, const float* __restrict__ uT,
    const float* __restrict__ W2, float* __restrict__ sraw) {
  __shared__ float Tl[HH][72];
  __shared__ float Ul[HH][72];
  __shared__ float PA[16][64];
  __shared__ float PB[16][64];
  __shared__ float As[64], Bs[64];

  const int tid = threadIdx.x;
  const int tx  = tid & 15;     // j-group (4 j)
  const int iy  = tid >> 4;     // i, 0..63
  const int i0  = blockIdx.y * 64;
  const int j0  = blockIdx.x * 64;

  // stage panels (pure float4 copies; t/u stored transposed in ws)
  #pragma unroll
  for (int s = 0; s < 4; ++s) {
    const int m = s * 1024 + tid;   // 0..4095
    const int h = m >> 4;
    const int g = m & 15;
    *(float4*)&Tl[h][4 * g] = *(const float4*)(tT + (size_t)h * LL + i0 + 4 * g);
    *(float4*)&Ul[h][4 * g] = *(const float4*)(uT + (size_t)h * LL + j0 + 4 * g);
  }
  __syncthreads();

  // rank-1 prologue: each wave owns one 16-h slice for one i/j column set
  {
    const int il = tid & 63, hq = tid >> 6;   // hq 0..15
    float pa = 0.f, pb = 0.f;
    #pragma unroll
    for (int n = 0; n < 16; ++n) {
      const int h = hq * 16 + n;
      const float w = W2[h];
      pa = fmaf(Tl[h][il], w, pa);
      pb = fmaf(Ul[h][il], w, pb);
    }
    PA[hq][il] = pa;
    PB[hq][il] = pb;
  }
  __syncthreads();
  if (tid < 128) {
    const int il = tid & 63;
    const float* Pp = (tid < 64) ? &PA[0][0] : &PB[0][0];
    float sum = 0.f;
    #pragma unroll
    for (int q = 0; q < 16; ++q) sum += Pp[q * 64 + il];
    if (tid < 64) As[il] = sum; else Bs[il] = sum;
  }
  __syncthreads();

  float acc[4] = {0.f, 0.f, 0.f, 0.f};

  #pragma unroll 8
  for (int h = 0; h < HH; ++h) {
    const float tv = Tl[h][iy];
    const float4 uv = *(const float4*)&Ul[h][4 * tx];
    const float w = W2[h];
    acc[0] = fmaf(fabsf(tv + uv.x), w, acc[0]);
    acc[1] = fmaf(fabsf(tv + uv.y), w, acc[1]);
    acc[2] = fmaf(fabsf(tv + uv.z), w, acc[2]);
    acc[3] = fmaf(fabsf(tv + uv.w), w, acc[3]);
  }

  const float Ai = As[iy];
  float4 v;
  v.x = 0.5f * (acc[0] + Ai + Bs[4 * tx + 0]);
  v.y = 0.5f * (acc[1] + Ai + Bs[4 * tx + 1]);
  v.z = 0.5f * (acc[2] + Ai + Bs[4 * tx + 2]);
  v.w = 0.5f * (acc[3] + Ai + Bs[4 * tx + 3]);
  *(float4*)(sraw + (size_t)(i0 + iy) * LL + j0 + 4 * tx) = v;
}

// ---------------------------------------------------------------------------
// Kernel 3: out = sigmoid(0.5*(s + s^T) + b2). 64x64 tiles, grid (16,16),
// 1024 threads (16 waves/CU), 1 float4 per thread per phase.
// ---------------------------------------------------------------------------
__global__ __launch_bounds__(1024) void sp_symsig(
    const float* __restrict__ sraw, const float* __restrict__ b2,
    float* __restrict__ out) {
  __shared__ float B[64][65];
  const int i0 = blockIdx.y * 64;
  const int j0 = blockIdx.x * 64;
  const int r  = threadIdx.x >> 4;   // 0..63
  const int g  = threadIdx.x & 15;   // 0..15

  const float4 bt = *(const float4*)(sraw + (size_t)(j0 + r) * LL + i0 + 4 * g);
  B[r][4 * g + 0] = bt.x;
  B[r][4 * g + 1] = bt.y;
  B[r][4 * g + 2] = bt.z;
  B[r][4 * g + 3] = bt.w;
  __syncthreads();

  const float4 a = *(const float4*)(sraw + (size_t)(i0 + r) * LL + j0 + 4 * g);
  const float bb = b2[0];
  float4 o;
  float x;
  x = 0.5f * (a.x + B[4 * g + 0][r]) + bb; o.x = 1.f / (1.f + expf(-x));
  x = 0.5f * (a.y + B[4 * g + 1][r]) + bb; o.y = 1.f / (1.f + expf(-x));
  x = 0.5f * (a.z + B[4 * g + 2][r]) + bb; o.z = 1.f / (1.f + expf(-x));
  x = 0.5f * (a.w + B[4 * g + 3][r]) + bb; o.w = 1.f / (1.f + expf(-x));
  *(float4*)(out + (size_t)(i0 + r) * LL + j0 + 4 * g) = o;
}

// ---------------------------------------------------------------------------
extern "C" void kernel_launch(void* const* d_in, const int* in_sizes, int n_in,
                              void* d_out, int out_size, void* d_ws, size_t ws_size,
                              hipStream_t stream) {
  const float* S  = (const float*)d_in[0];   // [L, D]
  const float* W1 = (const float*)d_in[1];   // [H, 2D]
  const float* b1 = (const float*)d_in[2];   // [H]
  const float* W2 = (const float*)d_in[3];   // [1, H]
  const float* b2 = (const float*)d_in[4];   // [1]
  float* out = (float*)d_out;

  float* ws = (float*)d_ws;
  float* tT   = ws;                  // [H][L]
  float* uT   = ws + HH * LL;        // [H][L]
  float* sraw = ws + 2 * HH * LL;    // [L][L]

  hipLaunchKernelGGL(sp_gemm, dim3(32, 16), dim3(256), 0, stream,
                     S, W1, b1, tT, uT);
  hipLaunchKernelGGL(sp_pairwise, dim3(16, 16), dim3(1024), 0, stream,
                     tT, uT, W2, sraw);
  hipLaunchKernelGGL(sp_symsig, dim3(16, 16), dim3(1024), 0, stream,
                     sraw, b2, out);
}

// Round 7
// 54.963 us; speedup vs baseline: 1.9083x; 1.0253x over previous
//
#include <hip/hip_runtime.h>
#include <math.h>

#define LL 1024
#define DD 512
#define HH 256
#define HL (HH * LL)

// ws layout (floats):
//   pz : [4][L][L]    @ 0          (16 MB) pairwise partials
//   pC : [4][512][L]  @ 0          (8 MB)  gemm partials -- OVERLAYS pz:
//                                   dead after sp_reduce, before sp_pairwise
//   O  : [512][L]     @ 4*L*L      (2 MB)  rows 0:256 = t(+b1), 256:512 = u
// total 18.9 MB

// ---------------------------------------------------------------------------
// Kernel 1: GEMM  C[i][n] = sum_k S[i][k] * W1[n&255][(n>>8)*512 + k]
// (n = mat*256+h merges the t/u outputs). M=1024, N=512, K=512 split 4.
// Tile 128i x 64n x 128k, 512 thr, 4i x 4n per thread (i=4ty+a blocked,
// n=tx+16b strided -> pad-36 rows give 2-way/broadcast LDS reads, free).
// grid (8,8,4)=256 blocks = 1/CU = 8 waves/CU = 2/SIMD.
// 8 b128 per 64 FMAs -> VALU-bound (round-6 gemm was 4 reads/16 FMAs).
// ---------------------------------------------------------------------------
__global__ __launch_bounds__(512) void sp_gemm(
    const float* __restrict__ S, const float* __restrict__ W1,
    float* __restrict__ pC) {
  __shared__ float Sl[2][128][36];   // 36.9 KB
  __shared__ float Wl[2][64][36];    // 18.4 KB

  const int tid = threadIdx.x;
  const int tx  = tid & 15;          // n = n0 + tx + 16b
  const int ty  = tid >> 4;          // i = i0 + 4ty + a, ty 0..31
  const int i0  = blockIdx.x * 128;
  const int n0  = blockIdx.y * 64;
  const int kz  = blockIdx.z * 128;

  // staging coords: per 32-k chunk S = 128x8 f4 (2/thr), W = 64x8 f4 (1/thr)
  const int srow = tid >> 3;         // 0..63
  const int ssl  = tid & 7;
  const int wn   = n0 + srow;        // global n for W staging
  const float* s0 = S + (size_t)(i0 + srow) * DD + kz + 4 * ssl;
  const float* s1 = S + (size_t)(i0 + 64 + srow) * DD + kz + 4 * ssl;
  const float* w0 = W1 + (size_t)(wn & 255) * (2 * DD) + (wn >> 8) * DD + kz + 4 * ssl;

  float4 sA, sB, wA;
  auto ld = [&](int c) {
    sA = *(const float4*)(s0 + 32 * c);
    sB = *(const float4*)(s1 + 32 * c);
    wA = *(const float4*)(w0 + 32 * c);
  };
  auto st = [&](int b) {
    *(float4*)&Sl[b][srow][4 * ssl]      = sA;
    *(float4*)&Sl[b][64 + srow][4 * ssl] = sB;
    *(float4*)&Wl[b][srow][4 * ssl]      = wA;
  };

  float acc[4][4] = {{0.f}};

  ld(0); st(0); __syncthreads();

  for (int c = 0; c < 4; ++c) {
    const int cur = c & 1;
    if (c < 3) ld(c + 1);
    #pragma unroll 2
    for (int k4 = 0; k4 < 8; ++k4) {
      float4 wf[4], sf[4];
      #pragma unroll
      for (int b = 0; b < 4; ++b) wf[b] = *(const float4*)&Wl[cur][tx + 16 * b][4 * k4];
      #pragma unroll
      for (int a = 0; a < 4; ++a) sf[a] = *(const float4*)&Sl[cur][4 * ty + a][4 * k4];
      #pragma unroll
      for (int a = 0; a < 4; ++a) {
        #pragma unroll
        for (int b = 0; b < 4; ++b) {
          acc[a][b] += sf[a].x * wf[b].x + sf[a].y * wf[b].y +
                       sf[a].z * wf[b].z + sf[a].w * wf[b].w;
        }
      }
    }
    if (c < 3) st(cur ^ 1);
    __syncthreads();
  }

  float* base = pC + (size_t)blockIdx.z * (512 * LL);
  #pragma unroll
  for (int b = 0; b < 4; ++b) {
    const int n = n0 + tx + 16 * b;
    *(float4*)(base + (size_t)n * LL + i0 + 4 * ty) =
        make_float4(acc[0][b], acc[1][b], acc[2][b], acc[3][b]);
  }
}

// ---------------------------------------------------------------------------
// Kernel 2: O[n][i] = sum_z pC[z][n][i]  (+ b1[n] for n<256).
// 512 blocks x 256 thr, 1 f4 each. ~10 MB L2 traffic.
// ---------------------------------------------------------------------------
__global__ __launch_bounds__(256) void sp_reduce(
    const float* __restrict__ pC, const float* __restrict__ b1,
    float* __restrict__ O) {
  const int m = blockIdx.x * 256 + threadIdx.x;  // 0..131071 f4
  const int n = m >> 8;
  const int NW = 512 * 256;                      // f4 per partial
  const float4* p = (const float4*)pC + m;
  float4 a  = p[0];
  float4 v1 = p[NW], v2 = p[2 * NW], v3 = p[3 * NW];
  a.x += v1.x + v2.x + v3.x;
  a.y += v1.y + v2.y + v3.y;
  a.z += v1.z + v2.z + v3.z;
  a.w += v1.w + v2.w + v3.w;
  if (n < 256) {
    const float bb = b1[n];
    a.x += bb; a.y += bb; a.z += bb; a.w += bb;
  }
  ((float4*)O)[m] = a;
}

// ---------------------------------------------------------------------------
// Kernel 3: pairwise. pz(i,j) = sum_{h in z}(|t+u|*w) + A_z(i) + B_z(j),
// where relu = 0.5(x+|x|) gives s = 0.5*sum_z pz (0.25 folded into symsig).
// Tile 128i x 64j, h-slice 64, grid (16 j, 8 i, 4 z) = 512 blocks = 2/CU
// = 8 waves/CU = 2/SIMD. 8i x 4j per thread: 3 b128 per 64 VALU ops,
// conflict-free (t: banks 0..31 exactly once; u: 2-way free).
// ---------------------------------------------------------------------------
__global__ __launch_bounds__(256) void sp_pairwise(
    const float* __restrict__ O, const float* __restrict__ W2,
    float* __restrict__ pz) {
  __shared__ float Tl[64][136];   // 34.8 KB
  __shared__ float Ul[64][72];    // 18.4 KB
  __shared__ float PA[2][128];
  __shared__ float PB[4][64];
  __shared__ float As[128];
  __shared__ float Bs[64];

  const int tid = threadIdx.x;
  const int tx  = tid & 15;       // j = j0 + 4tx
  const int ty  = tid >> 4;       // i = i0 + 8ty + a, ty 0..15
  const int j0  = blockIdx.x * 64;
  const int i0  = blockIdx.y * 128;
  const int hz  = blockIdx.z * 64;

  const float* tT = O;            // [256][L]
  const float* uT = O + HL;       // [256][L]

  // stage T: 64h x 128i = 2048 f4 (8/thr); U: 64h x 64j = 1024 f4 (4/thr)
  #pragma unroll
  for (int q = 0; q < 8; ++q) {
    const int m = q * 256 + tid;
    const int hh = m >> 5, g = m & 31;
    *(float4*)&Tl[hh][4 * g] = *(const float4*)(tT + (size_t)(hz + hh) * LL + i0 + 4 * g);
  }
  #pragma unroll
  for (int q = 0; q < 4; ++q) {
    const int m = q * 256 + tid;
    const int hh = m >> 4, g = m & 15;
    *(float4*)&Ul[hh][4 * g] = *(const float4*)(uT + (size_t)(hz + hh) * LL + j0 + 4 * g);
  }
  __syncthreads();

  // rank-1 prologue over this h-slice
  {
    const int il = tid & 127, p = tid >> 7;
    float s = 0.f;
    #pragma unroll 8
    for (int n = 0; n < 32; ++n) {
      const int hh = p * 32 + n;
      s = fmaf(Tl[hh][il], W2[hz + hh], s);
    }
    PA[p][il] = s;
    const int jl = tid & 63, q = tid >> 6;
    float sb = 0.f;
    #pragma unroll 8
    for (int n = 0; n < 16; ++n) {
      const int hh = q * 16 + n;
      sb = fmaf(Ul[hh][jl], W2[hz + hh], sb);
    }
    PB[q][jl] = sb;
  }
  __syncthreads();
  if (tid < 128) {
    As[tid] = PA[0][tid] + PA[1][tid];
  } else if (tid < 192) {
    const int j = tid - 128;
    Bs[j] = PB[0][j] + PB[1][j] + PB[2][j] + PB[3][j];
  }
  __syncthreads();

  float acc[8][4] = {{0.f}};

  #pragma unroll 4
  for (int hh = 0; hh < 64; ++hh) {
    const float w = W2[hz + hh];
    const float4 t0 = *(const float4*)&Tl[hh][8 * ty];
    const float4 t1 = *(const float4*)&Tl[hh][8 * ty + 4];
    const float4 uv = *(const float4*)&Ul[hh][4 * tx];
    const float tv[8] = {t0.x, t0.y, t0.z, t0.w, t1.x, t1.y, t1.z, t1.w};
    const float uvv[4] = {uv.x, uv.y, uv.z, uv.w};
    #pragma unroll
    for (int a = 0; a < 8; ++a) {
      #pragma unroll
      for (int b = 0; b < 4; ++b) {
        acc[a][b] = fmaf(fabsf(tv[a] + uvv[b]), w, acc[a][b]);
      }
    }
  }

  float* po = pz + (size_t)blockIdx.z * ((size_t)LL * LL);
  #pragma unroll
  for (int a = 0; a < 8; ++a) {
    const int i = i0 + 8 * ty + a;
    const float Ai = As[8 * ty + a];
    float4 v;
    v.x = acc[a][0] + Ai + Bs[4 * tx + 0];
    v.y = acc[a][1] + Ai + Bs[4 * tx + 1];
    v.z = acc[a][2] + Ai + Bs[4 * tx + 2];
    v.w = acc[a][3] + Ai + Bs[4 * tx + 3];
    *(float4*)(po + (size_t)i * LL + j0 + 4 * tx) = v;
  }
}

// ---------------------------------------------------------------------------
// Kernel 4: out = sigmoid(0.25*sum_z(pz(i,j)+pz(j,i)) + b2).
// 64x64 tiles, grid (16,16), 1024 thr (round-6 structure + 4-z merge).
// ---------------------------------------------------------------------------
__global__ __launch_bounds__(1024) void sp_symsig(
    const float* __restrict__ pz, const float* __restrict__ b2,
    float* __restrict__ out) {
  __shared__ float B[64][65];
  const int i0 = blockIdx.y * 64;
  const int j0 = blockIdx.x * 64;
  const int r  = threadIdx.x >> 4;   // 0..63
  const int g  = threadIdx.x & 15;   // 0..15
  const size_t L2 = (size_t)LL * LL;

  const float* pm = pz + (size_t)(j0 + r) * LL + i0 + 4 * g;
  const float4 m0 = *(const float4*)(pm);
  const float4 m1 = *(const float4*)(pm + L2);
  const float4 m2 = *(const float4*)(pm + 2 * L2);
  const float4 m3 = *(const float4*)(pm + 3 * L2);
  B[r][4 * g + 0] = m0.x + m1.x + m2.x + m3.x;
  B[r][4 * g + 1] = m0.y + m1.y + m2.y + m3.y;
  B[r][4 * g + 2] = m0.z + m1.z + m2.z + m3.z;
  B[r][4 * g + 3] = m0.w + m1.w + m2.w + m3.w;
  __syncthreads();

  const float* pd = pz + (size_t)(i0 + r) * LL + j0 + 4 * g;
  const float4 d0 = *(const float4*)(pd);
  const float4 d1 = *(const float4*)(pd + L2);
  const float4 d2 = *(const float4*)(pd + 2 * L2);
  const float4 d3 = *(const float4*)(pd + 3 * L2);
  const float bb = b2[0];
  float4 o;
  float x;
  x = 0.25f * (d0.x + d1.x + d2.x + d3.x + B[4 * g + 0][r]) + bb; o.x = 1.f / (1.f + expf(-x));
  x = 0.25f * (d0.y + d1.y + d2.y + d3.y + B[4 * g + 1][r]) + bb; o.y = 1.f / (1.f + expf(-x));
  x = 0.25f * (d0.z + d1.z + d2.z + d3.z + B[4 * g + 2][r]) + bb; o.z = 1.f / (1.f + expf(-x));
  x = 0.25f * (d0.w + d1.w + d2.w + d3.w + B[4 * g + 3][r]) + bb; o.w = 1.f / (1.f + expf(-x));
  *(float4*)(out + (size_t)(i0 + r) * LL + j0 + 4 * g) = o;
}

// ---------------------------------------------------------------------------
extern "C" void kernel_launch(void* const* d_in, const int* in_sizes, int n_in,
                              void* d_out, int out_size, void* d_ws, size_t ws_size,
                              hipStream_t stream) {
  const float* S  = (const float*)d_in[0];   // [L, D]
  const float* W1 = (const float*)d_in[1];   // [H, 2D]
  const float* b1 = (const float*)d_in[2];   // [H]
  const float* W2 = (const float*)d_in[3];   // [1, H]
  const float* b2 = (const float*)d_in[4];   // [1]
  float* out = (float*)d_out;

  float* ws = (float*)d_ws;
  float* pz = ws;                            // [4][L][L]  (16 MB)
  float* pC = ws;                            // [4][512][L] overlays pz (dead before pz written)
  float* O  = ws + 4 * (size_t)LL * LL;      // [512][L]

  hipLaunchKernelGGL(sp_gemm, dim3(8, 8, 4), dim3(512), 0, stream,
                     S, W1, pC);
  hipLaunchKernelGGL(sp_reduce, dim3(512), dim3(256), 0, stream,
                     pC, b1, O);
  hipLaunchKernelGGL(sp_pairwise, dim3(16, 8, 4), dim3(256), 0, stream,
                     O, W2, pz);
  hipLaunchKernelGGL(sp_symsig, dim3(16, 16), dim3(1024), 0, stream,
                     pz, b2, out);
}

// Round 8
// 49.934 us; speedup vs baseline: 2.1004x; 1.1007x over previous
//
#include <hip/hip_runtime.h>
#include <math.h>

#define LL 1024
#define DD 512
#define HH 256

// ws layout (floats):
//   O    : [512][1024] @ 0          rows 0:256 = t (+b1), 256:512 = u   (2 MB)
//   sraw : [1024][1024] @ 512*1024  P(i,j) = A_i + B_j + sum_h |t+u|w   (4 MB)

// ---------------------------------------------------------------------------
// Kernel 1: full-K GEMM -> O. tile 64i x 32n (n = mat*256+h merges t/u),
// K=512 in 16 chunks of 32, double-buffered LDS. 512 thr, grid (16,16)=256
// blocks = 1/CU = 8 waves/CU = 2/SIMD. Per thread 2i x 2n = 4 acc (~40 VGPR,
// no spill). Pad-36 rows: all LDS reads/writes 2-way max (free).
// ---------------------------------------------------------------------------
__global__ __launch_bounds__(512) void sp_gemm(
    const float* __restrict__ S, const float* __restrict__ W1,
    const float* __restrict__ b1, float* __restrict__ O) {
  __shared__ float Sl[2][64][36];   // 18.4 KB
  __shared__ float Wl[2][32][36];   //  9.2 KB

  const int tid = threadIdx.x;
  const int tx  = tid & 15;         // n = n0 + tx + 16b
  const int ty  = tid >> 4;         // i = i0 + 2ty + a, ty 0..31
  const int i0  = blockIdx.x * 64;
  const int n0  = blockIdx.y * 32;

  const int srow = tid >> 3;        // 0..63
  const int sc   = tid & 7;         // 0..7
  const int wn   = n0 + ((tid >> 3) & 31);
  const float* sp = S  + (size_t)(i0 + srow) * DD + 4 * sc;
  const float* wp = W1 + (size_t)(wn & 255) * (2 * DD) + (wn >> 8) * DD + 4 * sc;

  float4 sreg, wreg;
  auto ld = [&](int c) {
    sreg = *(const float4*)(sp + 32 * c);
    if (tid < 256) wreg = *(const float4*)(wp + 32 * c);
  };
  auto st = [&](int b) {
    *(float4*)&Sl[b][srow][4 * sc] = sreg;
    if (tid < 256) *(float4*)&Wl[b][tid >> 3][4 * sc] = wreg;
  };

  float acc[2][2] = {{0.f}};

  ld(0); st(0); __syncthreads();

  for (int c = 0; c < 16; ++c) {
    const int cur = c & 1;
    if (c < 15) ld(c + 1);          // next chunk's loads fly under compute
    #pragma unroll
    for (int k4 = 0; k4 < 8; ++k4) {
      const float4 wf0 = *(const float4*)&Wl[cur][tx][4 * k4];
      const float4 wf1 = *(const float4*)&Wl[cur][tx + 16][4 * k4];
      const float4 sf0 = *(const float4*)&Sl[cur][2 * ty][4 * k4];
      const float4 sf1 = *(const float4*)&Sl[cur][2 * ty + 1][4 * k4];
      acc[0][0] += sf0.x * wf0.x + sf0.y * wf0.y + sf0.z * wf0.z + sf0.w * wf0.w;
      acc[0][1] += sf0.x * wf1.x + sf0.y * wf1.y + sf0.z * wf1.z + sf0.w * wf1.w;
      acc[1][0] += sf1.x * wf0.x + sf1.y * wf0.y + sf1.z * wf0.z + sf1.w * wf0.w;
      acc[1][1] += sf1.x * wf1.x + sf1.y * wf1.y + sf1.z * wf1.z + sf1.w * wf1.w;
    }
    if (c < 15) st(cur ^ 1);        // safe: prev barrier drained buf cur^1
    __syncthreads();
  }

  #pragma unroll
  for (int b = 0; b < 2; ++b) {
    const int n = n0 + tx + 16 * b;
    const float bb = (n < 256) ? b1[n] : 0.f;
    float2 v = make_float2(acc[0][b] + bb, acc[1][b] + bb);
    *(float2*)(O + (size_t)n * LL + i0 + 2 * ty) = v;
  }
}

// ---------------------------------------------------------------------------
// Kernel 2: pairwise. P(i,j) = A_i + B_j + sum_h |t_i+u_j|*w2_h  where
// relu(x)=(x+|x|)/2 gives raw = P/2 (0.25 total folded into symsig).
// A_i = sum_h t_i w2, B_j = sum_h u_j w2 (rank-1, computed in prologue).
// 1024 thr (16 waves/CU = 4/SIMD), tile 64x64, grid (16,16)=256, 2i x 2j
// per thread. fp32 LDS panels [256][72] x2 = 147 KB (1 block/CU).
// Inner: 2 ds_b64 + 4 add + 4 fma(|src|) per h -> VALU-bound.
// ---------------------------------------------------------------------------
__global__ __launch_bounds__(1024) void sp_pairwise(
    const float* __restrict__ O, const float* __restrict__ W2,
    float* __restrict__ sraw) {
  __shared__ float Tl[HH][72];
  __shared__ float Ul[HH][72];
  __shared__ float PA[8][128];
  __shared__ float As[64], Bs[64];

  const int tid = threadIdx.x;
  const int tx  = tid & 31;     // j = j0 + 2tx + {0,1}
  const int ty  = tid >> 5;     // i = i0 + 2ty + {0,1}, 0..31
  const int i0  = blockIdx.y * 64;
  const int j0  = blockIdx.x * 64;

  // stage panels: T from O rows 0:256, U from rows 256:512 (f4 copies)
  #pragma unroll
  for (int q = 0; q < 4; ++q) {
    const int m = q * 1024 + tid;   // 0..4095
    const int h = m >> 4, g = m & 15;
    *(float4*)&Tl[h][4 * g] = *(const float4*)(O + (size_t)h * LL + i0 + 4 * g);
    *(float4*)&Ul[h][4 * g] = *(const float4*)(O + (size_t)(HH + h) * LL + j0 + 4 * g);
  }
  __syncthreads();

  // rank-1 prologue: 128 cols x 8 h-slices (wave-uniform panel select)
  {
    const int x = tid & 127, hs = tid >> 7;
    const float* pan = (x < 64) ? &Tl[0][x] : &Ul[0][x - 64];
    float p = 0.f;
    #pragma unroll 8
    for (int n = 0; n < 32; ++n) {
      const int h = hs * 32 + n;
      p = fmaf(pan[h * 72], W2[h], p);
    }
    PA[hs][x] = p;
  }
  __syncthreads();
  if (tid < 128) {
    float s = 0.f;
    #pragma unroll
    for (int q = 0; q < 8; ++q) s += PA[q][tid];
    if (tid < 64) As[tid] = s; else Bs[tid - 64] = s;
  }
  __syncthreads();

  float a00 = 0.f, a01 = 0.f, a10 = 0.f, a11 = 0.f;

  #pragma unroll 4
  for (int h = 0; h < HH; ++h) {
    const float2 tv = *(const float2*)&Tl[h][2 * ty];
    const float2 uv = *(const float2*)&Ul[h][2 * tx];
    const float w = W2[h];
    a00 = fmaf(fabsf(tv.x + uv.x), w, a00);
    a01 = fmaf(fabsf(tv.x + uv.y), w, a01);
    a10 = fmaf(fabsf(tv.y + uv.x), w, a10);
    a11 = fmaf(fabsf(tv.y + uv.y), w, a11);
  }

  const float A0 = As[2 * ty], A1 = As[2 * ty + 1];
  const float B0 = Bs[2 * tx], B1 = Bs[2 * tx + 1];
  float* p0 = sraw + (size_t)(i0 + 2 * ty) * LL + j0 + 2 * tx;
  *(float2*)p0        = make_float2(a00 + A0 + B0, a01 + A0 + B1);
  *(float2*)(p0 + LL) = make_float2(a10 + A1 + B0, a11 + A1 + B1);
}

// ---------------------------------------------------------------------------
// Kernel 3: out = sigmoid(0.25*(P + P^T) + b2). 64x64 tiles, grid (16,16),
// 1024 thr, LDS transpose (proven round-6 structure).
// ---------------------------------------------------------------------------
__global__ __launch_bounds__(1024) void sp_symsig(
    const float* __restrict__ sraw, const float* __restrict__ b2,
    float* __restrict__ out) {
  __shared__ float B[64][65];
  const int i0 = blockIdx.y * 64;
  const int j0 = blockIdx.x * 64;
  const int r  = threadIdx.x >> 4;   // 0..63
  const int g  = threadIdx.x & 15;   // 0..15

  const float4 bt = *(const float4*)(sraw + (size_t)(j0 + r) * LL + i0 + 4 * g);
  B[r][4 * g + 0] = bt.x;
  B[r][4 * g + 1] = bt.y;
  B[r][4 * g + 2] = bt.z;
  B[r][4 * g + 3] = bt.w;
  __syncthreads();

  const float4 a = *(const float4*)(sraw + (size_t)(i0 + r) * LL + j0 + 4 * g);
  const float bb = b2[0];
  float4 o;
  float x;
  x = 0.25f * (a.x + B[4 * g + 0][r]) + bb; o.x = 1.f / (1.f + expf(-x));
  x = 0.25f * (a.y + B[4 * g + 1][r]) + bb; o.y = 1.f / (1.f + expf(-x));
  x = 0.25f * (a.z + B[4 * g + 2][r]) + bb; o.z = 1.f / (1.f + expf(-x));
  x = 0.25f * (a.w + B[4 * g + 3][r]) + bb; o.w = 1.f / (1.f + expf(-x));
  *(float4*)(out + (size_t)(i0 + r) * LL + j0 + 4 * g) = o;
}

// ---------------------------------------------------------------------------
extern "C" void kernel_launch(void* const* d_in, const int* in_sizes, int n_in,
                              void* d_out, int out_size, void* d_ws, size_t ws_size,
                              hipStream_t stream) {
  const float* S  = (const float*)d_in[0];   // [L, D]
  const float* W1 = (const float*)d_in[1];   // [H, 2D]
  const float* b1 = (const float*)d_in[2];   // [H]
  const float* W2 = (const float*)d_in[3];   // [1, H]
  const float* b2 = (const float*)d_in[4];   // [1]
  float* out = (float*)d_out;

  float* ws   = (float*)d_ws;
  float* O    = ws;                      // [512][1024]
  float* sraw = ws + 512 * LL;           // [1024][1024]

  hipLaunchKernelGGL(sp_gemm, dim3(16, 16), dim3(512), 0, stream,
                     S, W1, b1, O);
  hipLaunchKernelGGL(sp_pairwise, dim3(16, 16), dim3(1024), 0, stream,
                     O, W2, sraw);
  hipLaunchKernelGGL(sp_symsig, dim3(16, 16), dim3(1024), 0, stream,
                     sraw, b2, out);
}